// Round 1
// 648.630 us; speedup vs baseline: 1.1026x; 1.1026x over previous
//
#include <hip/hip_runtime.h>

typedef short short8 __attribute__((ext_vector_type(8)));
typedef short short4v __attribute__((ext_vector_type(4)));
typedef float f32x4 __attribute__((ext_vector_type(4)));

#define T_SEQ 2048
#define C_DIM 2048
#define H_NUM 16
#define D_HEAD 128
#define B_NUM 4
#define M_ROWS (B_NUM * T_SEQ)   // 8192

__device__ __forceinline__ unsigned short f2bf(float f) {
    union { float f; unsigned u; } v; v.f = f;
    unsigned r = v.u + 0x7FFFu + ((v.u >> 16) & 1u);
    return (unsigned short)(r >> 16);
}
__device__ __forceinline__ float bf2f(unsigned short u) {
    union { unsigned u; float f; } v; v.u = ((unsigned)u) << 16;
    return v.f;
}

// async global->LDS, 16B per lane; lds ptr wave-uniform (HW adds lane*16)
__device__ __forceinline__ void async_ld16(const unsigned short* g, unsigned short* l) {
    __builtin_amdgcn_global_load_lds(
        (const __attribute__((address_space(1))) unsigned int*)g,
        (__attribute__((address_space(3))) unsigned int*)l,
        16, 0, 0);
}

__device__ __forceinline__ f32x4 pv_mfma(short4v v, short4v p, f32x4 c) {
#if __has_builtin(__builtin_amdgcn_mfma_f32_16x16x16bf16_1k)
    return __builtin_amdgcn_mfma_f32_16x16x16bf16_1k(v, p, c, 0, 0, 0);
#else
    short8 vf = {v[0], v[1], v[2], v[3], 0, 0, 0, 0};
    short8 pf = {p[0], p[1], p[2], p[3], 0, 0, 0, 0};
    return __builtin_amdgcn_mfma_f32_16x16x32_bf16(vf, pf, c, 0, 0, 0);
#endif
}

// ---------------- weight cast + transpose: wt[w][n][k] = W_w[k][n] (bf16) ----
__global__ __launch_bounds__(256) void wcast_kernel(const float* __restrict__ W0,
                                                    const float* __restrict__ W1,
                                                    const float* __restrict__ W2,
                                                    const float* __restrict__ W3,
                                                    unsigned short* __restrict__ wt) {
    __shared__ float tile[32][33];
    const float* W = (blockIdx.z == 0) ? W0 : (blockIdx.z == 1) ? W1 : (blockIdx.z == 2) ? W2 : W3;
    unsigned short* out = wt + (size_t)blockIdx.z * C_DIM * C_DIM;
    int tx = threadIdx.x, ty = threadIdx.y;      // block (32, 8)
    int n0 = blockIdx.x * 32, k0 = blockIdx.y * 32;
    #pragma unroll
    for (int j = 0; j < 32; j += 8)
        tile[ty + j][tx] = W[(size_t)(k0 + ty + j) * C_DIM + n0 + tx];
    __syncthreads();
    #pragma unroll
    for (int j = 0; j < 32; j += 8)
        out[(size_t)(n0 + ty + j) * C_DIM + k0 + tx] = f2bf(tile[tx][ty + j]);
}

// ---------------- LayerNorm -> bf16 ----------------------------------------
__global__ __launch_bounds__(256) void ln_kernel(const float* __restrict__ x,
                                                 const float* __restrict__ g,
                                                 const float* __restrict__ bta,
                                                 unsigned short* __restrict__ nx) {
    int row = blockIdx.x;
    int tid = threadIdx.x;
    const float* xr = x + (size_t)row * C_DIM;
    float4 v0 = *(const float4*)(xr + tid * 8);
    float4 v1 = *(const float4*)(xr + tid * 8 + 4);
    float s = v0.x + v0.y + v0.z + v0.w + v1.x + v1.y + v1.z + v1.w;
    float q = v0.x * v0.x + v0.y * v0.y + v0.z * v0.z + v0.w * v0.w +
              v1.x * v1.x + v1.y * v1.y + v1.z * v1.z + v1.w * v1.w;
    #pragma unroll
    for (int m = 32; m; m >>= 1) { s += __shfl_xor(s, m); q += __shfl_xor(q, m); }
    __shared__ float red[2][4];
    int wave = tid >> 6, lane = tid & 63;
    if (lane == 0) { red[0][wave] = s; red[1][wave] = q; }
    __syncthreads();
    s = red[0][0] + red[0][1] + red[0][2] + red[0][3];
    q = red[1][0] + red[1][1] + red[1][2] + red[1][3];
    float mu = s * (1.0f / C_DIM);
    float var = q * (1.0f / C_DIM) - mu * mu;
    float rstd = rsqrtf(var + 1e-5f);
    float4 g0 = *(const float4*)(g + tid * 8);
    float4 g1 = *(const float4*)(g + tid * 8 + 4);
    float4 b0 = *(const float4*)(bta + tid * 8);
    float4 b1 = *(const float4*)(bta + tid * 8 + 4);
    unsigned short o[8];
    o[0] = f2bf((v0.x - mu) * rstd * g0.x + b0.x);
    o[1] = f2bf((v0.y - mu) * rstd * g0.y + b0.y);
    o[2] = f2bf((v0.z - mu) * rstd * g0.z + b0.z);
    o[3] = f2bf((v0.w - mu) * rstd * g0.w + b0.w);
    o[4] = f2bf((v1.x - mu) * rstd * g1.x + b1.x);
    o[5] = f2bf((v1.y - mu) * rstd * g1.y + b1.y);
    o[6] = f2bf((v1.z - mu) * rstd * g1.z + b1.z);
    o[7] = f2bf((v1.w - mu) * rstd * g1.w + b1.w);
    uint4 pk;
    pk.x = (unsigned)o[0] | ((unsigned)o[1] << 16);
    pk.y = (unsigned)o[2] | ((unsigned)o[3] << 16);
    pk.z = (unsigned)o[4] | ((unsigned)o[5] << 16);
    pk.w = (unsigned)o[6] | ((unsigned)o[7] << 16);
    *(uint4*)(nx + (size_t)row * C_DIM + tid * 8) = pk;
}

// ============================================================================
// 256x256 / BK=64 / 8-wave / 8-phase GEMM core (HK-style schedule, plain HIP)
//
// LDS (dynamic, 128 KiB): 2 buffers x { A[256][64], B[256][64] } bf16.
//   Region offsets (elements): Ah0=0, Ah1=8192, Bh0=16384, Bh1=24576.
//   XOR chunk swizzle: 16B-chunk c of row r stored at slot c^(r&7); the
//   global source address is pre-swizzled (global_load_lds dest is linear).
// Waves: w = wm*?  -> wm=w>>2 (2), wn=w&3 (4). Interleaved quadrant split:
//   quadrant (qm,qn): A rows qm*128+wm*64+[0,64), B rows qn*128+wn*32+[0,32).
// Phase/quadrant order per K-tile t (reads from buf[t&1]):
//   ph1 Q(0,0): read A(qm0)+B(qn0);  stage (t+1).Bh1  -> buf[(t+1)&1]
//   ph2 Q(0,1): read B(qn1);         stage (t+2).Ah0  -> buf[t&1]   (Ah0 free after ph1)
//   ph3 Q(1,1): read A(qm1);         stage (t+2).Bh0  -> buf[t&1]   (Bh0 free after ph1)
//   ph4 Q(1,0): no reads;            stage (t+2).Ah1  -> buf[t&1]   (Ah1 free after ph3)
//   boundary: vmcnt(6) (= 3 half-tiles in flight, never 0 mid-loop) + barrier.
// Tile t's 4 halves are thus issued at t-2.ph2/ph3/ph4 and t-1.ph1; the
// vmcnt(6) at end of t-1 retires exactly through (t).Bh1 -> tile t resident.
// ============================================================================

#define GBK 64
#define GNT (C_DIM / GBK)        // 32 K-tiles
#define LDSH 32768               // elements per buffer

#define GFENCE __asm__ volatile("" ::: "memory")
#define GBAR do { GFENCE; __builtin_amdgcn_s_barrier(); GFENCE; } while (0)

__device__ __forceinline__ void stage_half(const unsigned short* g, unsigned short* l,
                                           int w, int lane) {
    const int r8 = lane >> 3, s = lane & 7;
    #pragma unroll
    for (int j = 0; j < 2; j++) {
        int row = j * 64 + w * 8 + r8;                       // 0..127 within half
        async_ld16(g + (size_t)row * C_DIM + ((s ^ (row & 7)) << 3),
                   l + (j * 64 + w * 8) * 64);               // wave-uniform dest
    }
}

__device__ __forceinline__ void read_afrag(const unsigned short* As, int qm, int wm,
                                           int lo, int quad, short8 af[4][2]) {
    #pragma unroll
    for (int mi = 0; mi < 4; mi++)
        #pragma unroll
        for (int ks = 0; ks < 2; ks++) {
            int row = qm * 128 + wm * 64 + mi * 16 + lo;     // row&7 == lo&7
            af[mi][ks] = *(const short8*)(As + row * 64 + ((((ks << 2) | quad) ^ (lo & 7)) << 3));
        }
}

__device__ __forceinline__ void read_bfrag(const unsigned short* Bs, int qn, int wn,
                                           int lo, int quad, short8 bf[2][2]) {
    #pragma unroll
    for (int ni = 0; ni < 2; ni++)
        #pragma unroll
        for (int ks = 0; ks < 2; ks++) {
            int row = qn * 128 + wn * 32 + ni * 16 + lo;     // row&7 == lo&7
            bf[ni][ks] = *(const short8*)(Bs + row * 64 + ((((ks << 2) | quad) ^ (lo & 7)) << 3));
        }
}

__device__ __forceinline__ void mfma16(const short8 af[4][2], const short8 bf[2][2],
                                       f32x4 acc[4][2]) {
    __builtin_amdgcn_s_setprio(1);
    #pragma unroll
    for (int mi = 0; mi < 4; mi++)
        #pragma unroll
        for (int ni = 0; ni < 2; ni++)
            #pragma unroll
            for (int ks = 0; ks < 2; ks++)
                acc[mi][ni] = __builtin_amdgcn_mfma_f32_16x16x32_bf16(af[mi][ks], bf[ni][ks],
                                                                      acc[mi][ni], 0, 0, 0);
    __builtin_amdgcn_s_setprio(0);
}

__device__ __forceinline__ void gemm_core256(const unsigned short* __restrict__ A,
                                             const unsigned short* __restrict__ Bt,
                                             unsigned short* lds,
                                             int rowBase, int colBase,
                                             f32x4 acc[2][2][4][2]) {
    const int tid = threadIdx.x;
    const int lane = tid & 63, w = tid >> 6;
    const int quad = lane >> 4, lo = lane & 15;
    const int wm = w >> 2, wn = w & 3;

    auto stA = [&](int t, int half) {
        stage_half(A + (size_t)(rowBase + half * 128) * C_DIM + t * GBK,
                   lds + (t & 1) * LDSH + half * 8192, w, lane);
    };
    auto stB = [&](int t, int half) {
        stage_half(Bt + (size_t)(colBase + half * 128) * C_DIM + t * GBK,
                   lds + (t & 1) * LDSH + 16384 + half * 8192, w, lane);
    };

    // prologue: t0 all 4 halves, then t1 {Ah0,Bh0,Ah1} -> 14 loads in flight.
    // vmcnt(6) retires the oldest 8 = all of t0; outstanding = t1's 3 halves
    // (exactly the steady-state queue shape).
    stA(0, 0); stB(0, 0); stA(0, 1); stB(0, 1);
    stA(1, 0); stB(1, 0); stA(1, 1);
    __builtin_amdgcn_s_waitcnt(0x3F76);            // vmcnt(6)
    GBAR;

    for (int t = 0; t < GNT; ++t) {
        const unsigned short* As = lds + (t & 1) * LDSH;
        const unsigned short* Bs = As + 16384;
        short8 af[4][2], bf0[2][2], bf1[2][2];

        // ---- phase 1: Q(0,0) ----
        read_afrag(As, 0, wm, lo, quad, af);
        read_bfrag(Bs, 0, wn, lo, quad, bf0);
        if (t + 1 < GNT) stB(t + 1, 1);
        GBAR;
        mfma16(af, bf0, acc[0][0]);
        GBAR;

        // ---- phase 2: Q(0,1) (af reused; Ah0 region now free -> stage ahead) ----
        read_bfrag(Bs, 1, wn, lo, quad, bf1);
        if (t + 2 < GNT) stA(t + 2, 0);
        GBAR;
        mfma16(af, bf1, acc[0][1]);
        GBAR;

        // ---- phase 3: Q(1,1) (bf1 reused) ----
        read_afrag(As, 1, wm, lo, quad, af);
        if (t + 2 < GNT) stB(t + 2, 0);
        GBAR;
        mfma16(af, bf1, acc[1][1]);
        GBAR;

        // ---- phase 4: Q(1,0) (af,bf0 reused; no LDS reads) ----
        if (t + 2 < GNT) stA(t + 2, 1);
        GBAR;
        mfma16(af, bf0, acc[1][0]);
        if (t < GNT - 2) __builtin_amdgcn_s_waitcnt(0x3F76);  // vmcnt(6): tile t+1 resident
        else             __builtin_amdgcn_s_waitcnt(0x3F70);  // tail: drain
        GBAR;
    }
}

// ---------------- fused QKV GEMM (N = 6144) ---------------------------------
__global__ __launch_bounds__(512, 2) void gemm_qkv(const unsigned short* __restrict__ A,
                                                   const unsigned short* __restrict__ Bt,
                                                   const float* __restrict__ bq,
                                                   const float* __restrict__ bk,
                                                   const float* __restrict__ bv,
                                                   unsigned short* __restrict__ qb,
                                                   unsigned short* __restrict__ kb,
                                                   unsigned short* __restrict__ vtb) {
    extern __shared__ unsigned short ldsbuf[];
    f32x4 acc[2][2][4][2] = {};
    const int bid = blockIdx.x;                   // 768 blocks, 768%8==0
    const int b2 = (bid & 7) * 96 + (bid >> 3);   // bijective XCD swizzle
    const int rowBase = (b2 / 24) * 256;
    const int colBase = (b2 % 24) * 256;
    gemm_core256(A, Bt, ldsbuf, rowBase, colBase, acc);

    const int lane = threadIdx.x & 63, w = threadIdx.x >> 6;
    const int quad = lane >> 4, lo = lane & 15;
    const int wm = w >> 2, wn = w & 3;
    const int which = colBase >> 11;              // 256-tiles never straddle 2048
    const float* bias = (which == 0) ? bq : (which == 1) ? bk : bv;
    #pragma unroll
    for (int qm = 0; qm < 2; qm++)
        #pragma unroll
        for (int qn = 0; qn < 2; qn++)
            #pragma unroll
            for (int mi = 0; mi < 4; mi++)
                #pragma unroll
                for (int ni = 0; ni < 2; ni++) {
                    int n = colBase + qn * 128 + wn * 32 + ni * 16 + lo;
                    int c = n & (C_DIM - 1), h = c >> 7, d = c & 127;
                    float bsv = bias[c];
                    #pragma unroll
                    for (int r = 0; r < 4; r++) {
                        int m = rowBase + qm * 128 + wm * 64 + mi * 16 + quad * 4 + r;
                        int bb = m >> 11, tt = m & (T_SEQ - 1);
                        unsigned short u = f2bf(acc[qm][qn][mi][ni][r] + bsv);
                        if (which == 2)
                            vtb[(size_t)((bb * H_NUM + h) * D_HEAD + d) * T_SEQ + tt] = u;
                        else if (which == 1)
                            kb[(size_t)((bb * H_NUM + h) * T_SEQ + tt) * D_HEAD + d] = u;
                        else
                            qb[(size_t)((bb * H_NUM + h) * T_SEQ + tt) * D_HEAD + d] = u;
                    }
                }
}

// ---------------- output GEMM + bias + residual -----------------------------
__global__ __launch_bounds__(512, 2) void gemm_out(const unsigned short* __restrict__ A,
                                                   const unsigned short* __restrict__ Bt,
                                                   const float* __restrict__ bo,
                                                   const float* __restrict__ x,
                                                   float* __restrict__ out) {
    extern __shared__ unsigned short ldsbuf[];
    f32x4 acc[2][2][4][2] = {};
    const int bid = blockIdx.x;                   // 256 blocks
    const int b2 = (bid & 7) * 32 + (bid >> 3);
    const int rowBase = (b2 / 8) * 256;
    const int colBase = (b2 % 8) * 256;
    gemm_core256(A, Bt, ldsbuf, rowBase, colBase, acc);

    const int lane = threadIdx.x & 63, w = threadIdx.x >> 6;
    const int quad = lane >> 4, lo = lane & 15;
    const int wm = w >> 2, wn = w & 3;
    #pragma unroll
    for (int qm = 0; qm < 2; qm++)
        #pragma unroll
        for (int qn = 0; qn < 2; qn++)
            #pragma unroll
            for (int mi = 0; mi < 4; mi++)
                #pragma unroll
                for (int ni = 0; ni < 2; ni++) {
                    int n = colBase + qn * 128 + wn * 32 + ni * 16 + lo;
                    float bsv = bo[n];
                    #pragma unroll
                    for (int r = 0; r < 4; r++) {
                        int m = rowBase + qm * 128 + wm * 64 + mi * 16 + quad * 4 + r;
                        size_t idx = (size_t)m * C_DIM + n;
                        out[idx] = x[idx] + acc[qm][qn][mi][ni][r] + bsv;
                    }
                }
}

// ---------------- RoPE (in-place, bf16) -------------------------------------
__global__ __launch_bounds__(256) void rope_kernel(unsigned short* __restrict__ qb,
                                                   unsigned short* __restrict__ kb) {
    const bool isk = (blockIdx.y != 0);
    unsigned short* p = isk ? kb : qb;
    const float osc = isk ? 1.0f : 0.12751736f;    // log2(e)/sqrt(128)
    int pidx = blockIdx.x * 256 + threadIdx.x;     // 0 .. B*H*T*64-1
    int dd = pidx & 63;
    int bht = pidx >> 6;
    int t = bht & (T_SEQ - 1);
    unsigned short* base = p + (size_t)bht * D_HEAD;
    float x0 = bf2f(base[dd]);
    float x1 = bf2f(base[dd + 64]);
    float inv = exp2f((float)dd * (-13.287712379549449f / 64.0f));  // 10000^(-dd/64)
    float ang = (float)t * inv;
    float sn = __sinf(ang), cs = __cosf(ang);
    base[dd]      = f2bf((x0 * cs - x1 * sn) * osc);
    base[dd + 64] = f2bf((x1 * cs + x0 * sn) * osc);
}

// ---------------- causal flash attention (v4, unchanged) ---------------------
__device__ __forceinline__ void attn_stage(const unsigned short* __restrict__ kh,
                                           const unsigned short* __restrict__ vh,
                                           int kt, unsigned short* Kd, unsigned short* Vd,
                                           int w, int lane) {
    const int l4 = lane >> 4, c16 = lane & 15;
    const int l8 = lane >> 3, c8 = lane & 7;
    #pragma unroll
    for (int j = 0; j < 2; j++) {
        int R = w * 8 + j * 4;                     // K rows R..R+3
        int row = R + l4;
        int cl = c16 ^ (row & 15);                 // LDS slot (row,cs) holds chunk cs^row15
        async_ld16(kh + (size_t)(kt * 64 + row) * D_HEAD + cl * 8, Kd + R * D_HEAD);
    }
    #pragma unroll
    for (int j = 0; j < 2; j++) {
        int o8 = w * 2 + j;                        // V 8-row chunk 0..15
        int row = o8 * 8 + l8;
        int gu = (2 * c8) ^ (row & 14);            // 8B-unit swizzle, even mask keeps pairs
        async_ld16(vh + (size_t)row * T_SEQ + kt * 64 + gu * 4, Vd + o8 * 512);
    }
}

__device__ __forceinline__ void attn_tile128(const unsigned short* __restrict__ qh,
                                             const unsigned short* __restrict__ kh,
                                             const unsigned short* __restrict__ vh,
                                             unsigned short* __restrict__ attn_out,
                                             int tile, int b, int h, int w, int quad,
                                             int lo, int lane,
                                             unsigned short* Kb, unsigned short* Vb) {
    const int G = tile * 128 + 16 * w;           // this wave's 16 q-rows
    const int a = (G + 15) >> 6;                 // last needed k-tile
    const int nkt = 2 * tile + 2;
    const int tq = G + lo;

    short8 qf[4];
    #pragma unroll
    for (int ks = 0; ks < 4; ks++)
        qf[ks] = *(const short8*)(qh + (size_t)(G + lo) * D_HEAD + ks * 32 + quad * 8);

    float m_i = -1e30f, l_i = 0.f;
    f32x4 o[8];
    #pragma unroll
    for (int dt = 0; dt < 8; dt++) o[dt] = (f32x4){0.f, 0.f, 0.f, 0.f};

    attn_stage(kh, vh, 0, Kb, Vb, w, lane);
    for (int kt = 0; kt < nkt; kt++) {
        const int cur = kt & 1;
        if (kt + 1 < nkt) {
            attn_stage(kh, vh, kt + 1, Kb + (cur ^ 1) * 8192, Vb + (cur ^ 1) * 8192, w, lane);
            __builtin_amdgcn_s_waitcnt(0x3F74);   // vmcnt(4): this tile's 4 loads done
        } else {
            __builtin_amdgcn_s_waitcnt(0x3F70);   // vmcnt(0)
        }
        __asm__ volatile("" ::: "memory");
        __builtin_amdgcn_s_barrier();
        __asm__ volatile("" ::: "memory");

        if (kt <= a) {                            // wave-uniform
            const unsigned short* Kc = Kb + cur * 8192;
            const unsigned short* Vc = Vb + cur * 8192;
            // QK: S^T[key][qrow] = K . Q^T
            f32x4 s[4];
            #pragma unroll
            for (int kg = 0; kg < 4; kg++) s[kg] = (f32x4){0.f, 0.f, 0.f, 0.f};
            #pragma unroll
            for (int kg = 0; kg < 4; kg++)
                #pragma unroll
                for (int ks = 0; ks < 4; ks++) {
                    int ch = (ks * 4 + quad) ^ lo;            // row&15 == lo
                    short8 kf = *(const short8*)(Kc + (kg * 16 + lo) * D_HEAD + ch * 8);
                    s[kg] = __builtin_amdgcn_mfma_f32_16x16x32_bf16(kf, qf[ks], s[kg], 0, 0, 0);
                }

            // online softmax (exp2 domain; scale folded into Q)
            const bool msk = (kt == a);
            float mx = -1e30f;
            #pragma unroll
            for (int kg = 0; kg < 4; kg++)
                #pragma unroll
                for (int r = 0; r < 4; r++) {
                    if (msk) {
                        int key = kt * 64 + kg * 16 + quad * 4 + r;
                        if (key > tq) s[kg][r] = -1e30f;
                    }
                    mx = fmaxf(mx, s[kg][r]);
                }
            mx = fmaxf(mx, __shfl_xor(mx, 16));
            mx = fmaxf(mx, __shfl_xor(mx, 32));
            float mnew = fmaxf(m_i, mx);
            float alpha = __builtin_amdgcn_exp2f(m_i - mnew);
            float sm = 0.f;
            short4v pp[4];
            #pragma unroll
            for (int kg = 0; kg < 4; kg++) {
                float p0 = __builtin_amdgcn_exp2f(s[kg][0] - mnew);
                float p1 = __builtin_amdgcn_exp2f(s[kg][1] - mnew);
                float p2 = __builtin_amdgcn_exp2f(s[kg][2] - mnew);
                float p3 = __builtin_amdgcn_exp2f(s[kg][3] - mnew);
                sm += (p0 + p1) + (p2 + p3);
                union { float f; unsigned u; } c0, c1, c2, c3;
                c0.f = p0; c1.f = p1; c2.f = p2; c3.f = p3;
                union { short4v s4; unsigned u[2]; } pu;
                pu.u[0] = (c0.u >> 16) | (c1.u & 0xFFFF0000u);   // truncated bf16
                pu.u[1] = (c2.u >> 16) | (c3.u & 0xFFFF0000u);
                pp[kg] = pu.s4;
            }
            sm += __shfl_xor(sm, 16);
            sm += __shfl_xor(sm, 32);
            l_i = l_i * alpha + sm;
            m_i = mnew;

            // PV: O^T[d][qrow] += V^T . P^T   (K=16 per key-group)
            #pragma unroll
            for (int dt = 0; dt < 8; dt++) {
                f32x4 oo = o[dt];
                #pragma unroll
                for (int r = 0; r < 4; r++) oo[r] *= alpha;
                #pragma unroll
                for (int kg = 0; kg < 4; kg++) {
                    int un = (kg * 4 + quad) ^ (lo & 14);     // vrow&14 == lo&14
                    short4v vv = *(const short4v*)(Vc + (dt * 16 + lo) * 64 + un * 4);
                    oo = pv_mfma(vv, pp[kg], oo);
                }
                o[dt] = oo;
            }
        }
        __asm__ volatile("" ::: "memory");
        __builtin_amdgcn_s_barrier();
        __asm__ volatile("" ::: "memory");
    }

    // epilogue: O^T C-layout lane(quad,lo): d = dt*16+quad*4+r, qrow = G+lo
    float inv_l = 1.f / l_i;
    size_t base = ((size_t)b * T_SEQ + G + lo) * C_DIM + h * D_HEAD + quad * 4;
    #pragma unroll
    for (int dt = 0; dt < 8; dt++) {
        uint2 u;
        u.x = (unsigned)f2bf(o[dt][0] * inv_l) | ((unsigned)f2bf(o[dt][1] * inv_l) << 16);
        u.y = (unsigned)f2bf(o[dt][2] * inv_l) | ((unsigned)f2bf(o[dt][3] * inv_l) << 16);
        *(uint2*)(attn_out + base + dt * 16) = u;
    }
}

__global__ __launch_bounds__(512, 4) void attn_kernel(const unsigned short* __restrict__ q,
                                                      const unsigned short* __restrict__ k,
                                                      const unsigned short* __restrict__ vt,
                                                      unsigned short* __restrict__ attn_out) {
    __shared__ unsigned short Kb[2 * 64 * 128];   // 32 KB
    __shared__ unsigned short Vb[2 * 128 * 64];   // 32 KB
    const int lane = threadIdx.x & 63;
    const int w = threadIdx.x >> 6;               // 0..7
    const int quad = lane >> 4, lo = lane & 15;
    const int bid = blockIdx.x;                   // 512 blocks = 2/CU
    const int head_lin = bid & 63;                // same head => same XCD (bid%8 const)
    const int pr = bid >> 6;                      // pair index 0..7
    const int b = head_lin >> 4, h = head_lin & 15;
    const unsigned short* qh = q + (size_t)head_lin * T_SEQ * D_HEAD;
    const unsigned short* kh = k + (size_t)head_lin * T_SEQ * D_HEAD;
    const unsigned short* vh = vt + (size_t)head_lin * D_HEAD * T_SEQ;

    attn_tile128(qh, kh, vh, attn_out, pr,      b, h, w, quad, lo, lane, Kb, Vb);  // light
    attn_tile128(qh, kh, vh, attn_out, 15 - pr, b, h, w, quad, lo, lane, Kb, Vb);  // heavy
}

// ---------------- launch -----------------------------------------------------
extern "C" void kernel_launch(void* const* d_in, const int* in_sizes, int n_in,
                              void* d_out, int out_size, void* d_ws, size_t ws_size,
                              hipStream_t stream) {
    const float* x    = (const float*)d_in[0];
    const float* ln_g = (const float*)d_in[1];
    const float* ln_b = (const float*)d_in[2];
    const float* Wq   = (const float*)d_in[3];
    const float* bq   = (const float*)d_in[4];
    const float* Wk   = (const float*)d_in[5];
    const float* bk   = (const float*)d_in[6];
    const float* Wv   = (const float*)d_in[7];
    const float* bv   = (const float*)d_in[8];
    const float* Wo   = (const float*)d_in[9];
    const float* bo   = (const float*)d_in[10];
    float* out = (float*)d_out;

    char* ws = (char*)d_ws;
    const size_t SZ = (size_t)M_ROWS * C_DIM * 2;        // 33,554,432 bytes
    unsigned short* nx  = (unsigned short*)(ws);
    unsigned short* wt  = (unsigned short*)(ws + SZ);    // 4 x 2048 x 2048 bf16
    unsigned short* qb  = (unsigned short*)(ws + 2 * SZ);
    unsigned short* kb  = (unsigned short*)(ws + 3 * SZ);
    unsigned short* vtb = (unsigned short*)(ws + 4 * SZ);
    unsigned short* at  = (unsigned short*)(ws + 5 * SZ);

    static bool lds_inited = false;
    if (!lds_inited) {
        hipFuncSetAttribute((const void*)gemm_qkv,
                            hipFuncAttributeMaxDynamicSharedMemorySize, 131072);
        hipFuncSetAttribute((const void*)gemm_out,
                            hipFuncAttributeMaxDynamicSharedMemorySize, 131072);
        lds_inited = true;
    }

    wcast_kernel<<<dim3(64, 64, 4), dim3(32, 8), 0, stream>>>(Wq, Wk, Wv, Wo, wt);
    ln_kernel<<<M_ROWS, 256, 0, stream>>>(x, ln_g, ln_b, nx);
    gemm_qkv<<<768, 512, 131072, stream>>>(nx, wt, bq, bk, bv, qb, kb, vtb);
    rope_kernel<<<dim3((B_NUM * H_NUM * T_SEQ * 64) / 256, 2), 256, 0, stream>>>(qb, kb);
    attn_kernel<<<512, 512, 0, stream>>>(qb, kb, vtb, at);
    gemm_out<<<256, 512, 131072, stream>>>(at, wt + (size_t)3 * C_DIM * C_DIM, bo, x, out);
}

// Round 2
// 618.933 us; speedup vs baseline: 1.1555x; 1.0480x over previous
//
#include <hip/hip_runtime.h>

typedef short short8 __attribute__((ext_vector_type(8)));
typedef short short4v __attribute__((ext_vector_type(4)));
typedef float f32x4 __attribute__((ext_vector_type(4)));

#define T_SEQ 2048
#define C_DIM 2048
#define H_NUM 16
#define D_HEAD 128
#define B_NUM 4
#define M_ROWS (B_NUM * T_SEQ)   // 8192

__device__ __forceinline__ unsigned short f2bf(float f) {
    union { float f; unsigned u; } v; v.f = f;
    unsigned r = v.u + 0x7FFFu + ((v.u >> 16) & 1u);
    return (unsigned short)(r >> 16);
}
__device__ __forceinline__ float bf2f(unsigned short u) {
    union { unsigned u; float f; } v; v.u = ((unsigned)u) << 16;
    return v.f;
}

// async global->LDS, 16B per lane; lds ptr wave-uniform (HW adds lane*16)
__device__ __forceinline__ void async_ld16(const unsigned short* g, unsigned short* l) {
    __builtin_amdgcn_global_load_lds(
        (const __attribute__((address_space(1))) unsigned int*)g,
        (__attribute__((address_space(3))) unsigned int*)l,
        16, 0, 0);
}

__device__ __forceinline__ f32x4 pv_mfma(short4v v, short4v p, f32x4 c) {
#if __has_builtin(__builtin_amdgcn_mfma_f32_16x16x16bf16_1k)
    return __builtin_amdgcn_mfma_f32_16x16x16bf16_1k(v, p, c, 0, 0, 0);
#else
    short8 vf = {v[0], v[1], v[2], v[3], 0, 0, 0, 0};
    short8 pf = {p[0], p[1], p[2], p[3], 0, 0, 0, 0};
    return __builtin_amdgcn_mfma_f32_16x16x32_bf16(vf, pf, c, 0, 0, 0);
#endif
}

// ---------------- weight cast + transpose: wt[w][n][k] = W_w[k][n] (bf16) ----
__global__ __launch_bounds__(256) void wcast_kernel(const float* __restrict__ W0,
                                                    const float* __restrict__ W1,
                                                    const float* __restrict__ W2,
                                                    const float* __restrict__ W3,
                                                    unsigned short* __restrict__ wt) {
    __shared__ float tile[32][33];
    const float* W = (blockIdx.z == 0) ? W0 : (blockIdx.z == 1) ? W1 : (blockIdx.z == 2) ? W2 : W3;
    unsigned short* out = wt + (size_t)blockIdx.z * C_DIM * C_DIM;
    int tx = threadIdx.x, ty = threadIdx.y;      // block (32, 8)
    int n0 = blockIdx.x * 32, k0 = blockIdx.y * 32;
    #pragma unroll
    for (int j = 0; j < 32; j += 8)
        tile[ty + j][tx] = W[(size_t)(k0 + ty + j) * C_DIM + n0 + tx];
    __syncthreads();
    #pragma unroll
    for (int j = 0; j < 32; j += 8)
        out[(size_t)(n0 + ty + j) * C_DIM + k0 + tx] = f2bf(tile[tx][ty + j]);
}

// ---------------- LayerNorm -> bf16 ----------------------------------------
__global__ __launch_bounds__(256) void ln_kernel(const float* __restrict__ x,
                                                 const float* __restrict__ g,
                                                 const float* __restrict__ bta,
                                                 unsigned short* __restrict__ nx) {
    int row = blockIdx.x;
    int tid = threadIdx.x;
    const float* xr = x + (size_t)row * C_DIM;
    float4 v0 = *(const float4*)(xr + tid * 8);
    float4 v1 = *(const float4*)(xr + tid * 8 + 4);
    float s = v0.x + v0.y + v0.z + v0.w + v1.x + v1.y + v1.z + v1.w;
    float q = v0.x * v0.x + v0.y * v0.y + v0.z * v0.z + v0.w * v0.w +
              v1.x * v1.x + v1.y * v1.y + v1.z * v1.z + v1.w * v1.w;
    #pragma unroll
    for (int m = 32; m; m >>= 1) { s += __shfl_xor(s, m); q += __shfl_xor(q, m); }
    __shared__ float red[2][4];
    int wave = tid >> 6, lane = tid & 63;
    if (lane == 0) { red[0][wave] = s; red[1][wave] = q; }
    __syncthreads();
    s = red[0][0] + red[0][1] + red[0][2] + red[0][3];
    q = red[1][0] + red[1][1] + red[1][2] + red[1][3];
    float mu = s * (1.0f / C_DIM);
    float var = q * (1.0f / C_DIM) - mu * mu;
    float rstd = rsqrtf(var + 1e-5f);
    float4 g0 = *(const float4*)(g + tid * 8);
    float4 g1 = *(const float4*)(g + tid * 8 + 4);
    float4 b0 = *(const float4*)(bta + tid * 8);
    float4 b1 = *(const float4*)(bta + tid * 8 + 4);
    unsigned short o[8];
    o[0] = f2bf((v0.x - mu) * rstd * g0.x + b0.x);
    o[1] = f2bf((v0.y - mu) * rstd * g0.y + b0.y);
    o[2] = f2bf((v0.z - mu) * rstd * g0.z + b0.z);
    o[3] = f2bf((v0.w - mu) * rstd * g0.w + b0.w);
    o[4] = f2bf((v1.x - mu) * rstd * g1.x + b1.x);
    o[5] = f2bf((v1.y - mu) * rstd * g1.y + b1.y);
    o[6] = f2bf((v1.z - mu) * rstd * g1.z + b1.z);
    o[7] = f2bf((v1.w - mu) * rstd * g1.w + b1.w);
    uint4 pk;
    pk.x = (unsigned)o[0] | ((unsigned)o[1] << 16);
    pk.y = (unsigned)o[2] | ((unsigned)o[3] << 16);
    pk.z = (unsigned)o[4] | ((unsigned)o[5] << 16);
    pk.w = (unsigned)o[6] | ((unsigned)o[7] << 16);
    *(uint4*)(nx + (size_t)row * C_DIM + tid * 8) = pk;
}

// ============================================================================
// 256x256 / BK=64 / 8-wave GEMM core, ONE barrier per phase.
//
// LDS (dynamic, 128 KiB): 2 buffers x { A[256][64], B[256][64] } bf16.
//   Region offsets (elements): Ah0=0, Ah1=8192, Bh0=16384, Bh1=24576.
//   XOR chunk swizzle: 16B-chunk c of row r at slot c^(r&7); global source
//   pre-swizzled (global_load_lds dest is linear).
// Phases per tile t (reads from buf[t&1]):
//   ph1 Q(0,0): rd A(qm0)+B(qn0); stage (t+1).Ah1 -> buf[(t+1)&1]; BAR; MFMA
//   ph2 Q(0,1): rd B(qn1);        stage (t+1).Bh1 -> buf[(t+1)&1]; BAR; MFMA
//   ph3 Q(1,1): rd A(qm1);        stage (t+2).Ah0 -> buf[t&1];     BAR; MFMA
//   ph4 Q(1,0): (reg reuse);      stage (t+2).Bh0 -> buf[t&1];     BAR; MFMA
//   boundary: vmcnt(4) + BAR  (4 ops = the two (t+2)-halves stay in flight)
// Hazard proof (stage-write vs LDS-read of same region):
//   (t+1).Ah1: last read t-1.ph3 -> >=2 barriers before issue at t.ph1
//   (t+1).Bh1: last read t-1.ph2 -> >=3 barriers
//   (t+2).Ah0: last read t.ph1   -> issued after t.ph2's barrier (2 barriers)
//   (t+2).Bh0: last read t.ph1   -> issued after t.ph3's barrier (3 barriers)
// Queue algebra: 12 ops at each boundary, vmcnt(4) retires 8 oldest =
//   exactly tile t+1's 4 halves -> resident; never drains to 0 mid-loop.
// Dropping the post-MFMA barriers lets phase k+1's ds_read burst overlap
// phase k's MFMA drain across waves (round-1 loss: bursts serialized).
// All ds_read addresses are one precomputed base + compile-time immediates:
//   addr = (base + qm*8192 + mi*1024) ^ (ks*32)  (adds never touch bits 3-5).
// ============================================================================

#define GBK 64
#define GNT (C_DIM / GBK)        // 32 K-tiles

#define GFENCE __asm__ volatile("" ::: "memory")
#define GBAR do { GFENCE; __builtin_amdgcn_s_barrier(); GFENCE; } while (0)

__device__ __forceinline__ void mfma16(const short8 af[4][2], const short8 bf[2][2],
                                       f32x4 acc[4][2]) {
    __builtin_amdgcn_s_setprio(1);
    #pragma unroll
    for (int mi = 0; mi < 4; mi++)
        #pragma unroll
        for (int ni = 0; ni < 2; ni++)
            #pragma unroll
            for (int ks = 0; ks < 2; ks++)
                acc[mi][ni] = __builtin_amdgcn_mfma_f32_16x16x32_bf16(af[mi][ks], bf[ni][ks],
                                                                      acc[mi][ni], 0, 0, 0);
    __builtin_amdgcn_s_setprio(0);
}

__device__ __forceinline__ void gemm_core256(const unsigned short* __restrict__ A,
                                             const unsigned short* __restrict__ Bt,
                                             unsigned short* lds,
                                             int rowBase, int colBase,
                                             f32x4 acc[2][2][4][2]) {
    const int tid = threadIdx.x;
    const int lane = tid & 63, w = tid >> 6;
    const int quad = lane >> 4, lo = lane & 15;
    const int wm = w >> 2, wn = w & 3;

    // precomputed LDS read bases (elements)
    const int swz8 = (quad ^ (lo & 7)) * 8;
    const int aoff = (wm * 64 + lo) * 64 + swz8;
    const int boff = (wn * 32 + lo) * 64 + swz8;

    // precomputed per-lane global stage offsets (elements) + LDS dest offsets
    const int r8 = lane >> 3, c8 = lane & 7;
    const int goff0 = (w * 8 + r8) * C_DIM + ((c8 ^ r8) << 3);
    const int goff1 = (64 + w * 8 + r8) * C_DIM + ((c8 ^ r8) << 3);
    const int ldst0 = (w * 8) * 64;
    const int ldst1 = (64 + w * 8) * 64;

    unsigned short* const L0 = lds;
    unsigned short* const L1 = lds + 32768;

    const unsigned short* gA0 = A + (size_t)rowBase * C_DIM;
    const unsigned short* gA1 = gA0 + (size_t)128 * C_DIM;
    const unsigned short* gB0 = Bt + (size_t)colBase * C_DIM;
    const unsigned short* gB1 = gB0 + (size_t)128 * C_DIM;

#define STAGE(gbase, lregion) do { \
        async_ld16((gbase) + goff0, (lregion) + ldst0); \
        async_ld16((gbase) + goff1, (lregion) + ldst1); \
    } while (0)

#define RDA(As, qm, dst) do { \
        _Pragma("unroll") \
        for (int mi = 0; mi < 4; mi++) { \
            dst[mi][0] = *(const short8*)((As) + (((qm) * 8192 + mi * 1024 + aoff))); \
            dst[mi][1] = *(const short8*)((As) + (((qm) * 8192 + mi * 1024 + aoff) ^ 32)); \
        } \
    } while (0)

#define RDB(Bs, qn, dst) do { \
        _Pragma("unroll") \
        for (int ni = 0; ni < 2; ni++) { \
            dst[ni][0] = *(const short8*)((Bs) + (((qn) * 8192 + ni * 1024 + boff))); \
            dst[ni][1] = *(const short8*)((Bs) + (((qn) * 8192 + ni * 1024 + boff) ^ 32)); \
        } \
    } while (0)

    // prologue: t0 all 4 halves + t1.{Ah0,Bh0}; vmcnt(4) -> t0 resident,
    // t1's two halves stay in flight (steady-state queue shape).
    STAGE(gA0,      L0);             // (0).Ah0
    STAGE(gB0,      L0 + 16384);     // (0).Bh0
    STAGE(gA1,      L0 + 8192);      // (0).Ah1
    STAGE(gB1,      L0 + 24576);     // (0).Bh1
    STAGE(gA0 + 64, L1);             // (1).Ah0
    STAGE(gB0 + 64, L1 + 16384);     // (1).Bh0
    __builtin_amdgcn_s_waitcnt(0x3F74);            // vmcnt(4)
    GBAR;

    for (int t = 0; t < GNT; ++t) {
        const unsigned short* As = (t & 1) ? L1 : L0;
        const unsigned short* Bs = As + 16384;
        unsigned short* Ln = (t & 1) ? L0 : L1;    // buf[(t+1)&1]
        unsigned short* Lc = (t & 1) ? L1 : L0;    // buf[t&1]
        short8 af[4][2], bf0[2][2], bf1[2][2];

        // ---- phase 1: Q(0,0); stage (t+1).Ah1 ----
        RDA(As, 0, af);
        RDB(Bs, 0, bf0);
        if (t + 1 < GNT) STAGE(gA1 + (t + 1) * GBK, Ln + 8192);
        GBAR;
        mfma16(af, bf0, acc[0][0]);

        // ---- phase 2: Q(0,1); stage (t+1).Bh1 ----
        RDB(Bs, 1, bf1);
        if (t + 1 < GNT) STAGE(gB1 + (t + 1) * GBK, Ln + 24576);
        GBAR;
        mfma16(af, bf1, acc[0][1]);

        // ---- phase 3: Q(1,1); stage (t+2).Ah0 ----
        RDA(As, 1, af);
        if (t + 2 < GNT) STAGE(gA0 + (t + 2) * GBK, Lc);
        GBAR;
        mfma16(af, bf1, acc[1][1]);

        // ---- phase 4: Q(1,0); stage (t+2).Bh0 ----
        if (t + 2 < GNT) STAGE(gB0 + (t + 2) * GBK, Lc + 16384);
        GBAR;
        mfma16(af, bf0, acc[1][0]);

        // ---- boundary: tile t+1 resident; keep (t+2) halves in flight ----
        if (t + 2 < GNT) __builtin_amdgcn_s_waitcnt(0x3F74);   // vmcnt(4)
        else             __builtin_amdgcn_s_waitcnt(0x3F70);   // vmcnt(0)
        GBAR;
    }
#undef STAGE
#undef RDA
#undef RDB
}

// ---------------- fused QKV GEMM (N = 6144) ---------------------------------
__global__ __launch_bounds__(512, 2) void gemm_qkv(const unsigned short* __restrict__ A,
                                                   const unsigned short* __restrict__ Bt,
                                                   const float* __restrict__ bq,
                                                   const float* __restrict__ bk,
                                                   const float* __restrict__ bv,
                                                   unsigned short* __restrict__ qb,
                                                   unsigned short* __restrict__ kb,
                                                   unsigned short* __restrict__ vtb) {
    extern __shared__ unsigned short ldsbuf[];
    f32x4 acc[2][2][4][2] = {};
    const int bid = blockIdx.x;                   // 768 blocks, 768%8==0
    const int b2 = (bid & 7) * 96 + (bid >> 3);   // bijective XCD swizzle
    const int rowBase = (b2 / 24) * 256;
    const int colBase = (b2 % 24) * 256;
    gemm_core256(A, Bt, ldsbuf, rowBase, colBase, acc);

    const int lane = threadIdx.x & 63, w = threadIdx.x >> 6;
    const int quad = lane >> 4, lo = lane & 15;
    const int wm = w >> 2, wn = w & 3;
    const int which = colBase >> 11;              // 256-tiles never straddle 2048
    const float* bias = (which == 0) ? bq : (which == 1) ? bk : bv;
    #pragma unroll
    for (int qm = 0; qm < 2; qm++)
        #pragma unroll
        for (int qn = 0; qn < 2; qn++)
            #pragma unroll
            for (int mi = 0; mi < 4; mi++)
                #pragma unroll
                for (int ni = 0; ni < 2; ni++) {
                    int n = colBase + qn * 128 + wn * 32 + ni * 16 + lo;
                    int c = n & (C_DIM - 1), h = c >> 7, d = c & 127;
                    float bsv = bias[c];
                    #pragma unroll
                    for (int r = 0; r < 4; r++) {
                        int m = rowBase + qm * 128 + wm * 64 + mi * 16 + quad * 4 + r;
                        int bb = m >> 11, tt = m & (T_SEQ - 1);
                        unsigned short u = f2bf(acc[qm][qn][mi][ni][r] + bsv);
                        if (which == 2)
                            vtb[(size_t)((bb * H_NUM + h) * D_HEAD + d) * T_SEQ + tt] = u;
                        else if (which == 1)
                            kb[(size_t)((bb * H_NUM + h) * T_SEQ + tt) * D_HEAD + d] = u;
                        else
                            qb[(size_t)((bb * H_NUM + h) * T_SEQ + tt) * D_HEAD + d] = u;
                    }
                }
}

// ---------------- output GEMM + bias + residual -----------------------------
__global__ __launch_bounds__(512, 2) void gemm_out(const unsigned short* __restrict__ A,
                                                   const unsigned short* __restrict__ Bt,
                                                   const float* __restrict__ bo,
                                                   const float* __restrict__ x,
                                                   float* __restrict__ out) {
    extern __shared__ unsigned short ldsbuf[];
    f32x4 acc[2][2][4][2] = {};
    const int bid = blockIdx.x;                   // 256 blocks
    const int b2 = (bid & 7) * 32 + (bid >> 3);
    const int rowBase = (b2 / 8) * 256;
    const int colBase = (b2 % 8) * 256;
    gemm_core256(A, Bt, ldsbuf, rowBase, colBase, acc);

    const int lane = threadIdx.x & 63, w = threadIdx.x >> 6;
    const int quad = lane >> 4, lo = lane & 15;
    const int wm = w >> 2, wn = w & 3;
    #pragma unroll
    for (int qm = 0; qm < 2; qm++)
        #pragma unroll
        for (int qn = 0; qn < 2; qn++)
            #pragma unroll
            for (int mi = 0; mi < 4; mi++)
                #pragma unroll
                for (int ni = 0; ni < 2; ni++) {
                    int n = colBase + qn * 128 + wn * 32 + ni * 16 + lo;
                    float bsv = bo[n];
                    #pragma unroll
                    for (int r = 0; r < 4; r++) {
                        int m = rowBase + qm * 128 + wm * 64 + mi * 16 + quad * 4 + r;
                        size_t idx = (size_t)m * C_DIM + n;
                        out[idx] = x[idx] + acc[qm][qn][mi][ni][r] + bsv;
                    }
                }
}

// ---------------- RoPE (in-place, bf16) -------------------------------------
__global__ __launch_bounds__(256) void rope_kernel(unsigned short* __restrict__ qb,
                                                   unsigned short* __restrict__ kb) {
    const bool isk = (blockIdx.y != 0);
    unsigned short* p = isk ? kb : qb;
    const float osc = isk ? 1.0f : 0.12751736f;    // log2(e)/sqrt(128)
    int pidx = blockIdx.x * 256 + threadIdx.x;     // 0 .. B*H*T*64-1
    int dd = pidx & 63;
    int bht = pidx >> 6;
    int t = bht & (T_SEQ - 1);
    unsigned short* base = p + (size_t)bht * D_HEAD;
    float x0 = bf2f(base[dd]);
    float x1 = bf2f(base[dd + 64]);
    float inv = exp2f((float)dd * (-13.287712379549449f / 64.0f));  // 10000^(-dd/64)
    float ang = (float)t * inv;
    float sn = __sinf(ang), cs = __cosf(ang);
    base[dd]      = f2bf((x0 * cs - x1 * sn) * osc);
    base[dd + 64] = f2bf((x1 * cs + x0 * sn) * osc);
}

// ---------------- causal flash attention (v4, unchanged) ---------------------
__device__ __forceinline__ void attn_stage(const unsigned short* __restrict__ kh,
                                           const unsigned short* __restrict__ vh,
                                           int kt, unsigned short* Kd, unsigned short* Vd,
                                           int w, int lane) {
    const int l4 = lane >> 4, c16 = lane & 15;
    const int l8 = lane >> 3, c8 = lane & 7;
    #pragma unroll
    for (int j = 0; j < 2; j++) {
        int R = w * 8 + j * 4;                     // K rows R..R+3
        int row = R + l4;
        int cl = c16 ^ (row & 15);                 // LDS slot (row,cs) holds chunk cs^row15
        async_ld16(kh + (size_t)(kt * 64 + row) * D_HEAD + cl * 8, Kd + R * D_HEAD);
    }
    #pragma unroll
    for (int j = 0; j < 2; j++) {
        int o8 = w * 2 + j;                        // V 8-row chunk 0..15
        int row = o8 * 8 + l8;
        int gu = (2 * c8) ^ (row & 14);            // 8B-unit swizzle, even mask keeps pairs
        async_ld16(vh + (size_t)row * T_SEQ + kt * 64 + gu * 4, Vd + o8 * 512);
    }
}

__device__ __forceinline__ void attn_tile128(const unsigned short* __restrict__ qh,
                                             const unsigned short* __restrict__ kh,
                                             const unsigned short* __restrict__ vh,
                                             unsigned short* __restrict__ attn_out,
                                             int tile, int b, int h, int w, int quad,
                                             int lo, int lane,
                                             unsigned short* Kb, unsigned short* Vb) {
    const int G = tile * 128 + 16 * w;           // this wave's 16 q-rows
    const int a = (G + 15) >> 6;                 // last needed k-tile
    const int nkt = 2 * tile + 2;
    const int tq = G + lo;

    short8 qf[4];
    #pragma unroll
    for (int ks = 0; ks < 4; ks++)
        qf[ks] = *(const short8*)(qh + (size_t)(G + lo) * D_HEAD + ks * 32 + quad * 8);

    float m_i = -1e30f, l_i = 0.f;
    f32x4 o[8];
    #pragma unroll
    for (int dt = 0; dt < 8; dt++) o[dt] = (f32x4){0.f, 0.f, 0.f, 0.f};

    attn_stage(kh, vh, 0, Kb, Vb, w, lane);
    for (int kt = 0; kt < nkt; kt++) {
        const int cur = kt & 1;
        if (kt + 1 < nkt) {
            attn_stage(kh, vh, kt + 1, Kb + (cur ^ 1) * 8192, Vb + (cur ^ 1) * 8192, w, lane);
            __builtin_amdgcn_s_waitcnt(0x3F74);   // vmcnt(4): this tile's 4 loads done
        } else {
            __builtin_amdgcn_s_waitcnt(0x3F70);   // vmcnt(0)
        }
        __asm__ volatile("" ::: "memory");
        __builtin_amdgcn_s_barrier();
        __asm__ volatile("" ::: "memory");

        if (kt <= a) {                            // wave-uniform
            const unsigned short* Kc = Kb + cur * 8192;
            const unsigned short* Vc = Vb + cur * 8192;
            // QK: S^T[key][qrow] = K . Q^T
            f32x4 s[4];
            #pragma unroll
            for (int kg = 0; kg < 4; kg++) s[kg] = (f32x4){0.f, 0.f, 0.f, 0.f};
            #pragma unroll
            for (int kg = 0; kg < 4; kg++)
                #pragma unroll
                for (int ks = 0; ks < 4; ks++) {
                    int ch = (ks * 4 + quad) ^ lo;            // row&15 == lo
                    short8 kf = *(const short8*)(Kc + (kg * 16 + lo) * D_HEAD + ch * 8);
                    s[kg] = __builtin_amdgcn_mfma_f32_16x16x32_bf16(kf, qf[ks], s[kg], 0, 0, 0);
                }

            // online softmax (exp2 domain; scale folded into Q)
            const bool msk = (kt == a);
            float mx = -1e30f;
            #pragma unroll
            for (int kg = 0; kg < 4; kg++)
                #pragma unroll
                for (int r = 0; r < 4; r++) {
                    if (msk) {
                        int key = kt * 64 + kg * 16 + quad * 4 + r;
                        if (key > tq) s[kg][r] = -1e30f;
                    }
                    mx = fmaxf(mx, s[kg][r]);
                }
            mx = fmaxf(mx, __shfl_xor(mx, 16));
            mx = fmaxf(mx, __shfl_xor(mx, 32));
            float mnew = fmaxf(m_i, mx);
            float alpha = __builtin_amdgcn_exp2f(m_i - mnew);
            float sm = 0.f;
            short4v pp[4];
            #pragma unroll
            for (int kg = 0; kg < 4; kg++) {
                float p0 = __builtin_amdgcn_exp2f(s[kg][0] - mnew);
                float p1 = __builtin_amdgcn_exp2f(s[kg][1] - mnew);
                float p2 = __builtin_amdgcn_exp2f(s[kg][2] - mnew);
                float p3 = __builtin_amdgcn_exp2f(s[kg][3] - mnew);
                sm += (p0 + p1) + (p2 + p3);
                union { float f; unsigned u; } c0, c1, c2, c3;
                c0.f = p0; c1.f = p1; c2.f = p2; c3.f = p3;
                union { short4v s4; unsigned u[2]; } pu;
                pu.u[0] = (c0.u >> 16) | (c1.u & 0xFFFF0000u);   // truncated bf16
                pu.u[1] = (c2.u >> 16) | (c3.u & 0xFFFF0000u);
                pp[kg] = pu.s4;
            }
            sm += __shfl_xor(sm, 16);
            sm += __shfl_xor(sm, 32);
            l_i = l_i * alpha + sm;
            m_i = mnew;

            // PV: O^T[d][qrow] += V^T . P^T   (K=16 per key-group)
            #pragma unroll
            for (int dt = 0; dt < 8; dt++) {
                f32x4 oo = o[dt];
                #pragma unroll
                for (int r = 0; r < 4; r++) oo[r] *= alpha;
                #pragma unroll
                for (int kg = 0; kg < 4; kg++) {
                    int un = (kg * 4 + quad) ^ (lo & 14);     // vrow&14 == lo&14
                    short4v vv = *(const short4v*)(Vc + (dt * 16 + lo) * 64 + un * 4);
                    oo = pv_mfma(vv, pp[kg], oo);
                }
                o[dt] = oo;
            }
        }
        __asm__ volatile("" ::: "memory");
        __builtin_amdgcn_s_barrier();
        __asm__ volatile("" ::: "memory");
    }

    // epilogue: O^T C-layout lane(quad,lo): d = dt*16+quad*4+r, qrow = G+lo
    float inv_l = 1.f / l_i;
    size_t base = ((size_t)b * T_SEQ + G + lo) * C_DIM + h * D_HEAD + quad * 4;
    #pragma unroll
    for (int dt = 0; dt < 8; dt++) {
        uint2 u;
        u.x = (unsigned)f2bf(o[dt][0] * inv_l) | ((unsigned)f2bf(o[dt][1] * inv_l) << 16);
        u.y = (unsigned)f2bf(o[dt][2] * inv_l) | ((unsigned)f2bf(o[dt][3] * inv_l) << 16);
        *(uint2*)(attn_out + base + dt * 16) = u;
    }
}

__global__ __launch_bounds__(512, 4) void attn_kernel(const unsigned short* __restrict__ q,
                                                      const unsigned short* __restrict__ k,
                                                      const unsigned short* __restrict__ vt,
                                                      unsigned short* __restrict__ attn_out) {
    __shared__ unsigned short Kb[2 * 64 * 128];   // 32 KB
    __shared__ unsigned short Vb[2 * 128 * 64];   // 32 KB
    const int lane = threadIdx.x & 63;
    const int w = threadIdx.x >> 6;               // 0..7
    const int quad = lane >> 4, lo = lane & 15;
    const int bid = blockIdx.x;                   // 512 blocks = 2/CU
    const int head_lin = bid & 63;                // same head => same XCD (bid%8 const)
    const int pr = bid >> 6;                      // pair index 0..7
    const int b = head_lin >> 4, h = head_lin & 15;
    const unsigned short* qh = q + (size_t)head_lin * T_SEQ * D_HEAD;
    const unsigned short* kh = k + (size_t)head_lin * T_SEQ * D_HEAD;
    const unsigned short* vh = vt + (size_t)head_lin * D_HEAD * T_SEQ;

    attn_tile128(qh, kh, vh, attn_out, pr,      b, h, w, quad, lo, lane, Kb, Vb);  // light
    attn_tile128(qh, kh, vh, attn_out, 15 - pr, b, h, w, quad, lo, lane, Kb, Vb);  // heavy
}

// ---------------- launch -----------------------------------------------------
extern "C" void kernel_launch(void* const* d_in, const int* in_sizes, int n_in,
                              void* d_out, int out_size, void* d_ws, size_t ws_size,
                              hipStream_t stream) {
    const float* x    = (const float*)d_in[0];
    const float* ln_g = (const float*)d_in[1];
    const float* ln_b = (const float*)d_in[2];
    const float* Wq   = (const float*)d_in[3];
    const float* bq   = (const float*)d_in[4];
    const float* Wk   = (const float*)d_in[5];
    const float* bk   = (const float*)d_in[6];
    const float* Wv   = (const float*)d_in[7];
    const float* bv   = (const float*)d_in[8];
    const float* Wo   = (const float*)d_in[9];
    const float* bo   = (const float*)d_in[10];
    float* out = (float*)d_out;

    char* ws = (char*)d_ws;
    const size_t SZ = (size_t)M_ROWS * C_DIM * 2;        // 33,554,432 bytes
    unsigned short* nx  = (unsigned short*)(ws);
    unsigned short* wt  = (unsigned short*)(ws + SZ);    // 4 x 2048 x 2048 bf16
    unsigned short* qb  = (unsigned short*)(ws + 2 * SZ);
    unsigned short* kb  = (unsigned short*)(ws + 3 * SZ);
    unsigned short* vtb = (unsigned short*)(ws + 4 * SZ);
    unsigned short* at  = (unsigned short*)(ws + 5 * SZ);

    static bool lds_inited = false;
    if (!lds_inited) {
        hipFuncSetAttribute((const void*)gemm_qkv,
                            hipFuncAttributeMaxDynamicSharedMemorySize, 131072);
        hipFuncSetAttribute((const void*)gemm_out,
                            hipFuncAttributeMaxDynamicSharedMemorySize, 131072);
        lds_inited = true;
    }

    wcast_kernel<<<dim3(64, 64, 4), dim3(32, 8), 0, stream>>>(Wq, Wk, Wv, Wo, wt);
    ln_kernel<<<M_ROWS, 256, 0, stream>>>(x, ln_g, ln_b, nx);
    gemm_qkv<<<768, 512, 131072, stream>>>(nx, wt, bq, bk, bv, qb, kb, vtb);
    rope_kernel<<<dim3((B_NUM * H_NUM * T_SEQ * 64) / 256, 2), 256, 0, stream>>>(qb, kb);
    attn_kernel<<<512, 512, 0, stream>>>(qb, kb, vtb, at);
    gemm_out<<<256, 512, 131072, stream>>>(at, wt + (size_t)3 * C_DIM * C_DIM, bo, x, out);
}